// Round 7
// baseline (175.806 us; speedup 1.0000x reference)
//
#include <hip/hip_runtime.h>
#include <hip/hip_bf16.h>

// Deformable conv2d (v1, align_corners=True, zeros padding), NHWC-bf16
// gather + MFMA. R7: barrier-free 2-deep gather software pipeline
// (G(kn+1) always in flight during interp(kn); steady-state vmcnt(8), never
// drained) + all A-fragments staged to LDS ONCE (single barrier; A reads on
// lgkmcnt so the vmcnt stream is pure gathers) + 18 offsets preloaded.
// Theory: R2-R6 all pinned at 45-50us because each wave consumed its 8
// scattered gathers immediately after issue -> ~33 concurrent line-fills/CU
// (Little's law at ~200cyc L2 latency). Doubling per-wave flight depth and
// removing competing VMEM should ~halve the exposed latency.
// x(4,64,128,128) f32, offset(4,18,128,128) f32, weight(64,64,9) f32
// -> out(4,64,128,128) f32.  iy = oh + off_y, ix = ow + off_x.

#define NB 4
#define CI 64
#define HH 128
#define WW 128
#define OCH 64
#define KNN 9
#define HW (HH * WW)

typedef unsigned int u32;
typedef unsigned short u16;
typedef __attribute__((ext_vector_type(8))) short bf16x8;
typedef __attribute__((ext_vector_type(4))) float f32x4;

typedef const __attribute__((address_space(1))) u32* gas_ptr;
typedef __attribute__((address_space(3))) u32* las_ptr;

__device__ inline u16 f2bf(float f) {  // RNE
    u32 u = __float_as_uint(f);
    return (u16)((u + 0x7fffu + ((u >> 16) & 1u)) >> 16);
}
__device__ inline u32 pk2(float lo, float hi) {
    return (u32)f2bf(lo) | ((u32)f2bf(hi) << 16);
}
__device__ inline void up2(u32 u, float& lo, float& hi) {
    lo = __uint_as_float(u << 16);
    hi = __uint_as_float(u & 0xffff0000u);
}
__device__ inline void gload_lds16(const u16* g, u16* s) {
    __builtin_amdgcn_global_load_lds((gas_ptr)g, (las_ptr)s, 16, 0, 0);
}

// ---- prologue: x NCHW f32 -> NHWC bf16, + weight -> A-fragment order bf16.
// wf layout: frag[kn][chunk(2)][strip(4)][lane(64)][j(8)]; lane holds
// A[m=lane&15][k=(lane>>4)*8+j], oc = strip*16+m, c = chunk*32+k.
__global__ __launch_bounds__(256) void prep_kernel(const float* __restrict__ x,
                                                   const float* __restrict__ w,
                                                   u16* __restrict__ xT,
                                                   u16* __restrict__ wf) {
    __shared__ float T[64 * 68];
    const int tid = threadIdx.x;
    if (blockIdx.x < NB * 256) {
        const int n = blockIdx.x >> 8;
        const int hw0 = (blockIdx.x & 255) << 6;
#pragma unroll
        for (int jj = 0; jj < 4; jj++) {
            int c = (tid >> 4) + (jj << 4);
            int hwq = (tid & 15) << 2;
            float4 v = *(const float4*)&x[(((n << 6) + c) << 14) + hw0 + hwq];
            *(float4*)&T[c * 68 + hwq] = v;
        }
        __syncthreads();
        const int hw_l = tid >> 2;
        const int cb = (tid & 3) << 4;
        u32 ou[8];
#pragma unroll
        for (int k = 0; k < 8; k++) {
            ou[k] = pk2(T[(cb + 2 * k) * 68 + hw_l], T[(cb + 2 * k + 1) * 68 + hw_l]);
        }
        u16* dst = xT + ((size_t)((n << 14) + hw0 + hw_l) << 6) + cb;
        *(uint4*)dst = make_uint4(ou[0], ou[1], ou[2], ou[3]);
        *(uint4*)(dst + 8) = make_uint4(ou[4], ou[5], ou[6], ou[7]);
    } else {
        int i = (blockIdx.x - NB * 256) * 256 + tid;
        if (i < KNN * 2 * 4 * 64 * 8) {
            int j = i & 7, l = (i >> 3) & 63, strip = (i >> 9) & 3,
                chunk = (i >> 11) & 1, kn = i >> 12;
            int oc = strip * 16 + (l & 15);
            int c = chunk * 32 + ((l >> 4) & 3) * 8 + j;
            wf[i] = f2bf(w[(oc * CI + c) * KNN + kn]);
        }
    }
}

// ---- main kernel: block = 8x8 pixel patch (4 waves of 4x4), 64 oc.
__global__ __launch_bounds__(256, 2) void dcn_main_kernel(const u16* __restrict__ xT,
                                                          const float* __restrict__ off,
                                                          const u16* __restrict__ wf,
                                                          float* __restrict__ out) {
    __shared__ __align__(16) u16 Abuf[KNN * 4096];  // all 9 kn A-fragments, 72 KB
    const int tid = threadIdx.x;
    const int l = tid & 63;
    const int wv = tid >> 6;

    // stage all A-fragments to LDS (vmcnt stream; drained by the one barrier)
    {
        const u16* g = wf + tid * 8;
        u16* s = Abuf + tid * 8;
#pragma unroll
        for (int i = 0; i < 18; i++) {
            gload_lds16(g + i * 2048, s + i * 2048);
        }
    }

    // XCD-affine decode (as R6): xcd = blockIdx&7; n = xcd>>1; half = xcd&1.
    const int b = blockIdx.x;
    const int xcd = b & 7;
    const int n = xcd >> 1;
    const int patch = (b >> 3) + ((xcd & 1) << 7);  // 0..255
    const int py = ((patch >> 4) << 3), px = ((patch & 15) << 3);
    const int qy = ((wv >> 1) << 2), qx = ((wv & 1) << 2);
    const int col = l & 15;
    const int oh = py + qy + (col >> 2);
    const int ow = px + qx + (col & 3);
    const int rr = (oh << 7) + ow;
    const int cbase = (l >> 4) << 3;  // 0,8,16,24
    const u16* xTn = xT + ((size_t)n << 20);
    const float* offn = off + n * (2 * KNN * HW);

    // preload all 18 offsets (also drained by the barrier)
    float offy[KNN], offx[KNN];
#pragma unroll
    for (int kn = 0; kn < KNN; kn++) {
        offy[kn] = offn[(2 * kn) * HW + rr];
        offx[kn] = offn[(2 * kn + 1) * HW + rr];
    }

    __syncthreads();  // A resident; offsets in regs; vmcnt clean

    f32x4 acc[4] = {{0, 0, 0, 0}, {0, 0, 0, 0}, {0, 0, 0, 0}, {0, 0, 0, 0}};

    float W[2][4];
    uint4 Q[2][8];

    auto coords_and_issue = [&](int kn) {
        const int p = kn & 1;
        float iy = (float)oh + offy[kn], ix = (float)ow + offx[kn];
        float y0f = floorf(iy), x0f = floorf(ix);
        float wy1 = iy - y0f, wy0 = 1.f - wy1;
        float wx1 = ix - x0f, wx0 = 1.f - wx1;
        float my0 = (y0f >= 0.f && y0f <= 127.f) ? 1.f : 0.f;
        float my1 = (y0f >= -1.f && y0f <= 126.f) ? 1.f : 0.f;
        float mx0 = (x0f >= 0.f && x0f <= 127.f) ? 1.f : 0.f;
        float mx1 = (x0f >= -1.f && x0f <= 126.f) ? 1.f : 0.f;
        W[p][0] = wy0 * wx0 * my0 * mx0;
        W[p][1] = wy0 * wx1 * my0 * mx1;
        W[p][2] = wy1 * wx0 * my1 * mx0;
        W[p][3] = wy1 * wx1 * my1 * mx1;
        int y0 = min(max((int)y0f, 0), 127), y1 = min(max((int)y0f + 1, 0), 127);
        int x0 = min(max((int)x0f, 0), 127), x1 = min(max((int)x0f + 1, 0), 127);
        const u16* p0 = xTn + (((y0 << 7) + x0) << 6) + cbase;
        const u16* p1 = xTn + (((y0 << 7) + x1) << 6) + cbase;
        const u16* p2 = xTn + (((y1 << 7) + x0) << 6) + cbase;
        const u16* p3 = xTn + (((y1 << 7) + x1) << 6) + cbase;
        Q[p][0] = *(const uint4*)(p0);
        Q[p][1] = *(const uint4*)(p1);
        Q[p][2] = *(const uint4*)(p2);
        Q[p][3] = *(const uint4*)(p3);
        Q[p][4] = *(const uint4*)(p0 + 32);
        Q[p][5] = *(const uint4*)(p1 + 32);
        Q[p][6] = *(const uint4*)(p2 + 32);
        Q[p][7] = *(const uint4*)(p3 + 32);
    };

    // prologue: fill both pipeline slots
    coords_and_issue(0);
    coords_and_issue(1);

#pragma unroll 1
    for (int kn = 0; kn < KNN; kn++) {
        const int p = kn & 1;
        // consume Q[p] into bf16 B fragments (this is where vmcnt(8) lands)
        union { u32 u[4]; bf16x8 v; } B0, B1;
#pragma unroll
        for (int k = 0; k < 4; k++) {
            float a0l, a0h, a1l, a1h, a2l, a2h, a3l, a3h;
            up2(((const u32*)&Q[p][0])[k], a0l, a0h);
            up2(((const u32*)&Q[p][1])[k], a1l, a1h);
            up2(((const u32*)&Q[p][2])[k], a2l, a2h);
            up2(((const u32*)&Q[p][3])[k], a3l, a3h);
            float slo = a0l * W[p][0] + a1l * W[p][1] + a2l * W[p][2] + a3l * W[p][3];
            float shi = a0h * W[p][0] + a1h * W[p][1] + a2h * W[p][2] + a3h * W[p][3];
            B0.u[k] = pk2(slo, shi);
        }
#pragma unroll
        for (int k = 0; k < 4; k++) {
            float a0l, a0h, a1l, a1h, a2l, a2h, a3l, a3h;
            up2(((const u32*)&Q[p][4])[k], a0l, a0h);
            up2(((const u32*)&Q[p][5])[k], a1l, a1h);
            up2(((const u32*)&Q[p][6])[k], a2l, a2h);
            up2(((const u32*)&Q[p][7])[k], a3l, a3h);
            float slo = a0l * W[p][0] + a1l * W[p][1] + a2l * W[p][2] + a3l * W[p][3];
            float shi = a0h * W[p][0] + a1h * W[p][1] + a2h * W[p][2] + a3h * W[p][3];
            B1.u[k] = pk2(slo, shi);
        }
        // Q[p] registers free -> refill with kn+2 (WAR safe: issued after reads)
        if (kn + 2 < KNN) coords_and_issue(kn + 2);
        // MFMA: A from LDS (lgkmcnt, independent of gather vmcnt)
#pragma unroll
        for (int s = 0; s < 4; s++) {
            bf16x8 A0 = *(const bf16x8*)&Abuf[(((kn << 1) + 0) << 2 | s) * 512 + l * 8];
            acc[s] = __builtin_amdgcn_mfma_f32_16x16x32_bf16(A0, B0.v, acc[s], 0, 0, 0);
        }
#pragma unroll
        for (int s = 0; s < 4; s++) {
            bf16x8 A1 = *(const bf16x8*)&Abuf[(((kn << 1) + 1) << 2 | s) * 512 + l * 8];
            acc[s] = __builtin_amdgcn_mfma_f32_16x16x32_bf16(A1, B1.v, acc[s], 0, 0, 0);
        }
    }

    // epilogue: D layout col(pixel)=l&15, row(oc-in-strip)=(l>>4)*4+reg
    const int rq = l >> 4;
    float* op = out + ((size_t)(n * OCH) << 14);
#pragma unroll
    for (int s = 0; s < 4; s++) {
        const int ocb = (s << 4) + (rq << 2);
#pragma unroll
        for (int g = 0; g < 4; g++) {
            op[((ocb + g) << 14) + rr] = acc[s][g];
        }
    }
}

// ---- fallback (ws too small): round-1 style direct kernel
__global__ __launch_bounds__(256) void dcn_fallback_kernel(
    const float* __restrict__ x, const float* __restrict__ off,
    const float* __restrict__ w, float* __restrict__ out) {
    int p = blockIdx.x * blockDim.x + threadIdx.x;
    int n = p / HW, r = p % HW, oh = r / WW, ow = r % WW;
    float acc[OCH];
#pragma unroll
    for (int i = 0; i < OCH; i++) acc[i] = 0.f;
    const float* xn = x + n * (CI * HW);
    const float* offn = off + n * (2 * KNN * HW);
    for (int kn = 0; kn < KNN; kn++) {
        float iy = (float)oh + offn[(2 * kn) * HW + r];
        float ix = (float)ow + offn[(2 * kn + 1) * HW + r];
        float y0f = floorf(iy), x0f = floorf(ix);
        float wy1 = iy - y0f, wy0 = 1.f - wy1, wx1 = ix - x0f, wx0 = 1.f - wx1;
        float my0 = (y0f >= 0.f && y0f <= 127.f) ? 1.f : 0.f;
        float my1 = (y0f >= -1.f && y0f <= 126.f) ? 1.f : 0.f;
        float mx0 = (x0f >= 0.f && x0f <= 127.f) ? 1.f : 0.f;
        float mx1 = (x0f >= -1.f && x0f <= 126.f) ? 1.f : 0.f;
        float w00 = wy0 * wx0 * my0 * mx0, w01 = wy0 * wx1 * my0 * mx1;
        float w10 = wy1 * wx0 * my1 * mx0, w11 = wy1 * wx1 * my1 * mx1;
        int y0 = min(max((int)y0f, 0), 127), y1 = min(max((int)y0f + 1, 0), 127);
        int x0 = min(max((int)x0f, 0), 127), x1 = min(max((int)x0f + 1, 0), 127);
        int o00 = y0 * WW + x0, o01 = y0 * WW + x1, o10 = y1 * WW + x0, o11 = y1 * WW + x1;
        for (int c = 0; c < CI; c++) {
            const float* xc = xn + c * HW;
            float s = xc[o00] * w00 + xc[o01] * w01 + xc[o10] * w10 + xc[o11] * w11;
#pragma unroll
            for (int oc = 0; oc < OCH; oc++) acc[oc] += w[(oc * CI + c) * KNN + kn] * s;
        }
    }
    float* outp = out + n * (OCH * HW) + r;
#pragma unroll
    for (int oc = 0; oc < OCH; oc++) outp[oc * HW] = acc[oc];
}

extern "C" void kernel_launch(void* const* d_in, const int* in_sizes, int n_in,
                              void* d_out, int out_size, void* d_ws, size_t ws_size,
                              hipStream_t stream) {
    const float* x = (const float*)d_in[0];
    const float* off = (const float*)d_in[1];
    const float* w = (const float*)d_in[2];
    float* out = (float*)d_out;

    const size_t xT_elems = (size_t)NB * HW * CI;             // 4,194,304 u16
    const size_t wf_elems = (size_t)KNN * 2 * 4 * 64 * 8;     // 36,864 u16
    const size_t need = (xT_elems + wf_elems) * sizeof(u16);  // ~8.46 MB

    if (ws_size >= need) {
        u16* xT = (u16*)d_ws;
        u16* wfr = xT + xT_elems;
        const int wf_blocks = (int)((wf_elems + 255) / 256);  // 144
        prep_kernel<<<NB * 256 + wf_blocks, 256, 0, stream>>>(x, w, xT, wfr);
        dcn_main_kernel<<<NB * 256, 256, 0, stream>>>(xT, off, wfr, out);
    } else {
        dcn_fallback_kernel<<<(NB * HW) / 256, 256, 0, stream>>>(x, off, w, out);
    }
}

// Round 8
// 102.298 us; speedup vs baseline: 1.7186x; 1.7186x over previous
//
#include <hip/hip_runtime.h>
#include <hip/hip_bf16.h>

// Deformable conv2d (v1, align_corners=True, zeros padding), NHWC-bf16 + MFMA.
// R8: LDS-resident input tile. Block = 8x8 output patch; its 16x16-pixel
// (4-px margin) x 64ch bf16 neighborhood is cooperatively loaded to LDS once
// (coalesced), and all bilinear corner reads are ds_read_b128. This cuts
// per-CU L1-missing scattered line-accesses ~9x (the R2-R6 invariant wall:
// ~18k lines/CU x ~200cyc / ~32 MSHRs ~= 46-50us regardless of structure).
// Samples outside the margin (|off|>~3, ~0.5%) take a rare exec-masked global
// gather fallback - exact semantics preserved.
// x(4,64,128,128) f32, offset(4,18,128,128) f32, weight(64,64,9) f32
// -> out(4,64,128,128) f32.  iy = oh + off_y, ix = ow + off_x.

#define NB 4
#define CI 64
#define HH 128
#define WW 128
#define OCH 64
#define KNN 9
#define HW (HH * WW)

typedef unsigned int u32;
typedef unsigned short u16;
typedef __attribute__((ext_vector_type(8))) short bf16x8;
typedef __attribute__((ext_vector_type(4))) float f32x4;

__device__ inline u16 f2bf(float f) {  // RNE
    u32 u = __float_as_uint(f);
    return (u16)((u + 0x7fffu + ((u >> 16) & 1u)) >> 16);
}
__device__ inline u32 pk2(float lo, float hi) {
    return (u32)f2bf(lo) | ((u32)f2bf(hi) << 16);
}
__device__ inline void up2(u32 u, float& lo, float& hi) {
    lo = __uint_as_float(u << 16);
    hi = __uint_as_float(u & 0xffff0000u);
}

// ---- prologue: x NCHW f32 -> NHWC bf16, + weight -> A-fragment order bf16.
// wf layout: frag[kn][chunk(2)][strip(4)][lane(64)][j(8)]; lane holds
// A[m=lane&15][k=(lane>>4)*8+j], oc = strip*16+m, c = chunk*32+k.
__global__ __launch_bounds__(256) void prep_kernel(const float* __restrict__ x,
                                                   const float* __restrict__ w,
                                                   u16* __restrict__ xT,
                                                   u16* __restrict__ wf) {
    __shared__ float T[64 * 68];
    const int tid = threadIdx.x;
    if (blockIdx.x < NB * 256) {
        const int n = blockIdx.x >> 8;
        const int hw0 = (blockIdx.x & 255) << 6;
#pragma unroll
        for (int jj = 0; jj < 4; jj++) {
            int c = (tid >> 4) + (jj << 4);
            int hwq = (tid & 15) << 2;
            float4 v = *(const float4*)&x[(((n << 6) + c) << 14) + hw0 + hwq];
            *(float4*)&T[c * 68 + hwq] = v;
        }
        __syncthreads();
        const int hw_l = tid >> 2;
        const int cb = (tid & 3) << 4;
        u32 ou[8];
#pragma unroll
        for (int k = 0; k < 8; k++) {
            ou[k] = pk2(T[(cb + 2 * k) * 68 + hw_l], T[(cb + 2 * k + 1) * 68 + hw_l]);
        }
        u16* dst = xT + ((size_t)((n << 14) + hw0 + hw_l) << 6) + cb;
        *(uint4*)dst = make_uint4(ou[0], ou[1], ou[2], ou[3]);
        *(uint4*)(dst + 8) = make_uint4(ou[4], ou[5], ou[6], ou[7]);
    } else {
        int i = (blockIdx.x - NB * 256) * 256 + tid;
        if (i < KNN * 2 * 4 * 64 * 8) {
            int j = i & 7, l = (i >> 3) & 63, strip = (i >> 9) & 3,
                chunk = (i >> 11) & 1, kn = i >> 12;
            int oc = strip * 16 + (l & 15);
            int c = chunk * 32 + ((l >> 4) & 3) * 8 + j;
            wf[i] = f2bf(w[(oc * CI + c) * KNN + kn]);
        }
    }
}

// ---- main kernel: block = 8x8 patch (4 waves of 4x4), 64 oc, LDS input tile.
__global__ __launch_bounds__(256, 3) void dcn_main_kernel(const u16* __restrict__ xT,
                                                          const float* __restrict__ off,
                                                          const u16* __restrict__ wf,
                                                          float* __restrict__ out) {
    // 16x16 pixels x (64ch + 8 pad) halfwords; stride 72 hw = 144 B = 36 dw.
    __shared__ __align__(16) u16 tile[256 * 72];  // 36,864 B
    const int tid = threadIdx.x;
    const int l = tid & 63;
    const int wv = tid >> 6;

    // XCD-affine decode (R6): xcd = blockIdx&7; n = xcd>>1; half = xcd&1.
    const int b = blockIdx.x;
    const int xcd = b & 7;
    const int n = xcd >> 1;
    const int patch = (b >> 3) + ((xcd & 1) << 7);  // 0..255
    const int py = ((patch >> 4) << 3), px = ((patch & 15) << 3);
    const int ty = min(max(py - 4, 0), HH - 16);
    const int tx = min(max(px - 4, 0), WW - 16);

    const u16* xTn = xT + ((size_t)n << 20);
    const float* offn = off + n * (2 * KNN * HW);

    // cooperative tile load: thread tid = tile pixel (tr,tc); 128 B each.
    {
        const int tr = tid >> 4, tc = tid & 15;
        const u16* src = xTn + ((((ty + tr) << 7) + (tx + tc)) << 6);
        u16* dst = &tile[tid * 72];
#pragma unroll
        for (int j = 0; j < 8; j++) {
            *(uint4*)(dst + j * 8) = *(const uint4*)(src + j * 8);
        }
    }

    const int qy = ((wv >> 1) << 2), qx = ((wv & 1) << 2);
    const int col = l & 15;
    const int oh = py + qy + (col >> 2);
    const int ow = px + qx + (col & 3);
    const int rr = (oh << 7) + ow;
    const int cbase = (l >> 4) << 3;  // 0,8,16,24 (halfwords)

    // preload all 18 offsets (overlaps the tile load)
    float offy[KNN], offx[KNN];
#pragma unroll
    for (int kn = 0; kn < KNN; kn++) {
        offy[kn] = offn[(2 * kn) * HW + rr];
        offx[kn] = offn[(2 * kn + 1) * HW + rr];
    }

    __syncthreads();  // tile resident

    const bf16x8* wfv = (const bf16x8*)wf;
    f32x4 acc[4] = {{0, 0, 0, 0}, {0, 0, 0, 0}, {0, 0, 0, 0}, {0, 0, 0, 0}};

#pragma unroll
    for (int kn = 0; kn < KNN; kn++) {
        float iy = (float)oh + offy[kn], ix = (float)ow + offx[kn];
        float y0f = floorf(iy), x0f = floorf(ix);
        float wy1 = iy - y0f, wy0 = 1.f - wy1;
        float wx1 = ix - x0f, wx0 = 1.f - wx1;
        float my0 = (y0f >= 0.f && y0f <= 127.f) ? 1.f : 0.f;
        float my1 = (y0f >= -1.f && y0f <= 126.f) ? 1.f : 0.f;
        float mx0 = (x0f >= 0.f && x0f <= 127.f) ? 1.f : 0.f;
        float mx1 = (x0f >= -1.f && x0f <= 126.f) ? 1.f : 0.f;
        float W0 = wy0 * wx0 * my0 * mx0, W1 = wy0 * wx1 * my0 * mx1;
        float W2 = wy1 * wx0 * my1 * mx0, W3 = wy1 * wx1 * my1 * mx1;
        int y0 = min(max((int)y0f, 0), 127), y1 = min(max((int)y0f + 1, 0), 127);
        int x0 = min(max((int)x0f, 0), 127), x1 = min(max((int)x0f + 1, 0), 127);

        // tile-local coords (clamped for LDS safety; oot lanes overwritten)
        const int dy0 = min(max(y0 - ty, 0), 15), dy1 = min(max(y1 - ty, 0), 15);
        const int dx0 = min(max(x0 - tx, 0), 15), dx1 = min(max(x1 - tx, 0), 15);
        const int p00 = (dy0 << 4) + dx0, p01 = (dy0 << 4) + dx1;
        const int p10 = (dy1 << 4) + dx0, p11 = (dy1 << 4) + dx1;
        const bool oot = (y0 < ty) | (y1 > ty + 15) | (x0 < tx) | (x1 > tx + 15);

        uint4 q[8];
        q[0] = *(const uint4*)&tile[p00 * 72 + cbase];
        q[1] = *(const uint4*)&tile[p01 * 72 + cbase];
        q[2] = *(const uint4*)&tile[p10 * 72 + cbase];
        q[3] = *(const uint4*)&tile[p11 * 72 + cbase];
        q[4] = *(const uint4*)&tile[p00 * 72 + cbase + 32];
        q[5] = *(const uint4*)&tile[p01 * 72 + cbase + 32];
        q[6] = *(const uint4*)&tile[p10 * 72 + cbase + 32];
        q[7] = *(const uint4*)&tile[p11 * 72 + cbase + 32];
        if (oot) {  // rare (~0.5% of lanes): exact global gather fallback
            const int O0 = ((y0 << 7) + x0) << 6, O1 = ((y0 << 7) + x1) << 6;
            const int O2 = ((y1 << 7) + x0) << 6, O3 = ((y1 << 7) + x1) << 6;
            q[0] = *(const uint4*)(xTn + O0 + cbase);
            q[1] = *(const uint4*)(xTn + O1 + cbase);
            q[2] = *(const uint4*)(xTn + O2 + cbase);
            q[3] = *(const uint4*)(xTn + O3 + cbase);
            q[4] = *(const uint4*)(xTn + O0 + cbase + 32);
            q[5] = *(const uint4*)(xTn + O1 + cbase + 32);
            q[6] = *(const uint4*)(xTn + O2 + cbase + 32);
            q[7] = *(const uint4*)(xTn + O3 + cbase + 32);
        }

#pragma unroll
        for (int ch = 0; ch < 2; ch++) {
            const u32* a0 = (const u32*)&q[ch * 4 + 0];
            const u32* a1 = (const u32*)&q[ch * 4 + 1];
            const u32* a2 = (const u32*)&q[ch * 4 + 2];
            const u32* a3 = (const u32*)&q[ch * 4 + 3];
            union { u32 u[4]; bf16x8 v; } B;
#pragma unroll
            for (int k = 0; k < 4; k++) {
                float p0l, p0h, p1l, p1h, p2l, p2h, p3l, p3h;
                up2(a0[k], p0l, p0h);
                up2(a1[k], p1l, p1h);
                up2(a2[k], p2l, p2h);
                up2(a3[k], p3l, p3h);
                float slo = p0l * W0 + p1l * W1 + p2l * W2 + p3l * W3;
                float shi = p0h * W0 + p1h * W1 + p2h * W2 + p3h * W3;
                B.u[k] = pk2(slo, shi);
            }
#pragma unroll
            for (int s = 0; s < 4; s++) {
                bf16x8 A = wfv[((((kn << 1) + ch) << 2) + s) * 64 + l];
                acc[s] = __builtin_amdgcn_mfma_f32_16x16x32_bf16(A, B.v, acc[s], 0, 0, 0);
            }
        }
    }

    // epilogue: D layout col(pixel)=l&15, row(oc-in-strip)=(l>>4)*4+reg
    const int rq = l >> 4;
    float* op = out + ((size_t)(n * OCH) << 14);
#pragma unroll
    for (int s = 0; s < 4; s++) {
        const int ocb = (s << 4) + (rq << 2);
#pragma unroll
        for (int g = 0; g < 4; g++) {
            op[((ocb + g) << 14) + rr] = acc[s][g];
        }
    }
}

// ---- fallback (ws too small): round-1 style direct kernel
__global__ __launch_bounds__(256) void dcn_fallback_kernel(
    const float* __restrict__ x, const float* __restrict__ off,
    const float* __restrict__ w, float* __restrict__ out) {
    int p = blockIdx.x * blockDim.x + threadIdx.x;
    int n = p / HW, r = p % HW, oh = r / WW, ow = r % WW;
    float acc[OCH];
#pragma unroll
    for (int i = 0; i < OCH; i++) acc[i] = 0.f;
    const float* xn = x + n * (CI * HW);
    const float* offn = off + n * (2 * KNN * HW);
    for (int kn = 0; kn < KNN; kn++) {
        float iy = (float)oh + offn[(2 * kn) * HW + r];
        float ix = (float)ow + offn[(2 * kn + 1) * HW + r];
        float y0f = floorf(iy), x0f = floorf(ix);
        float wy1 = iy - y0f, wy0 = 1.f - wy1, wx1 = ix - x0f, wx0 = 1.f - wx1;
        float my0 = (y0f >= 0.f && y0f <= 127.f) ? 1.f : 0.f;
        float my1 = (y0f >= -1.f && y0f <= 126.f) ? 1.f : 0.f;
        float mx0 = (x0f >= 0.f && x0f <= 127.f) ? 1.f : 0.f;
        float mx1 = (x0f >= -1.f && x0f <= 126.f) ? 1.f : 0.f;
        float w00 = wy0 * wx0 * my0 * mx0, w01 = wy0 * wx1 * my0 * mx1;
        float w10 = wy1 * wx0 * my1 * mx0, w11 = wy1 * wx1 * my1 * mx1;
        int y0 = min(max((int)y0f, 0), 127), y1 = min(max((int)y0f + 1, 0), 127);
        int x0 = min(max((int)x0f, 0), 127), x1 = min(max((int)x0f + 1, 0), 127);
        int o00 = y0 * WW + x0, o01 = y0 * WW + x1, o10 = y1 * WW + x0, o11 = y1 * WW + x1;
        for (int c = 0; c < CI; c++) {
            const float* xc = xn + c * HW;
            float s = xc[o00] * w00 + xc[o01] * w01 + xc[o10] * w10 + xc[o11] * w11;
#pragma unroll
            for (int oc = 0; oc < OCH; oc++) acc[oc] += w[(oc * CI + c) * KNN + kn] * s;
        }
    }
    float* outp = out + n * (OCH * HW) + r;
#pragma unroll
    for (int oc = 0; oc < OCH; oc++) outp[oc * HW] = acc[oc];
}

extern "C" void kernel_launch(void* const* d_in, const int* in_sizes, int n_in,
                              void* d_out, int out_size, void* d_ws, size_t ws_size,
                              hipStream_t stream) {
    const float* x = (const float*)d_in[0];
    const float* off = (const float*)d_in[1];
    const float* w = (const float*)d_in[2];
    float* out = (float*)d_out;

    const size_t xT_elems = (size_t)NB * HW * CI;             // 4,194,304 u16
    const size_t wf_elems = (size_t)KNN * 2 * 4 * 64 * 8;     // 36,864 u16
    const size_t need = (xT_elems + wf_elems) * sizeof(u16);  // ~8.46 MB

    if (ws_size >= need) {
        u16* xT = (u16*)d_ws;
        u16* wfr = xT + xT_elems;
        const int wf_blocks = (int)((wf_elems + 255) / 256);  // 144
        prep_kernel<<<NB * 256 + wf_blocks, 256, 0, stream>>>(x, w, xT, wfr);
        dcn_main_kernel<<<NB * 256, 256, 0, stream>>>(xT, off, wfr, out);
    } else {
        dcn_fallback_kernel<<<(NB * HW) / 256, 256, 0, stream>>>(x, off, w, out);
    }
}

// Round 9
// 101.460 us; speedup vs baseline: 1.7328x; 1.0083x over previous
//
#include <hip/hip_runtime.h>
#include <hip/hip_bf16.h>

// Deformable conv2d (v1, align_corners=True, zeros padding), NHWC-bf16 + MFMA.
// R9 = R8 (LDS input tile) with three measured-defect fixes:
//  (1) tile 14x16 px (30.5 KB) + __launch_bounds__(256,4): 4 blocks/CU all
//      resident, single dispatch pass (R8: 3+1 two-pass tail).
//  (2) tile stride 68 hw (34 dw, odd 8B-granule) + ds_read_b64 corner reads:
//      4-way bank aliasing instead of structural 8-way at 16B granules.
//  (3) bf16 pack via __float22bfloat162_rn (v_cvt_pk_bf16_f32) + float2
//      interp (v_pk_fma_f32): ~35% VALU cut vs manual RNE pack.
// x(4,64,128,128) f32, offset(4,18,128,128) f32, weight(64,64,9) f32
// -> out(4,64,128,128) f32.  iy = oh + off_y, ix = ow + off_x.

#define NB 4
#define CI 64
#define HH 128
#define WW 128
#define OCH 64
#define KNN 9
#define HW (HH * WW)
#define TSTR 68  // tile row stride in halfwords (34 dw, odd 8B-granule)

typedef unsigned int u32;
typedef unsigned short u16;
typedef __attribute__((ext_vector_type(8))) short bf16x8;
typedef __attribute__((ext_vector_type(4))) float f32x4;

__device__ inline u16 f2bf(float f) {  // RNE
    u32 u = __float_as_uint(f);
    return (u16)((u + 0x7fffu + ((u >> 16) & 1u)) >> 16);
}
__device__ inline u32 pk2(float lo, float hi) {
    return (u32)f2bf(lo) | ((u32)f2bf(hi) << 16);
}
__device__ inline float2 up2v(u32 u) {
    return float2{__uint_as_float(u << 16), __uint_as_float(u & 0xffff0000u)};
}
__device__ inline u32 pkrn(float2 s) {
    union { __hip_bfloat162 b; u32 u; } c;
    c.b = __float22bfloat162_rn(s);
    return c.u;
}

// ---- prologue: x NCHW f32 -> NHWC bf16, + weight -> A-fragment order bf16.
// wf layout: frag[kn][chunk(2)][strip(4)][lane(64)][j(8)]; lane holds
// A[m=lane&15][k=(lane>>4)*8+j], oc = strip*16+m, c = chunk*32+k.
__global__ __launch_bounds__(256) void prep_kernel(const float* __restrict__ x,
                                                   const float* __restrict__ w,
                                                   u16* __restrict__ xT,
                                                   u16* __restrict__ wf) {
    __shared__ float T[64 * 68];
    const int tid = threadIdx.x;
    if (blockIdx.x < NB * 256) {
        const int n = blockIdx.x >> 8;
        const int hw0 = (blockIdx.x & 255) << 6;
#pragma unroll
        for (int jj = 0; jj < 4; jj++) {
            int c = (tid >> 4) + (jj << 4);
            int hwq = (tid & 15) << 2;
            float4 v = *(const float4*)&x[(((n << 6) + c) << 14) + hw0 + hwq];
            *(float4*)&T[c * 68 + hwq] = v;
        }
        __syncthreads();
        const int hw_l = tid >> 2;
        const int cb = (tid & 3) << 4;
        u32 ou[8];
#pragma unroll
        for (int k = 0; k < 8; k++) {
            ou[k] = pk2(T[(cb + 2 * k) * 68 + hw_l], T[(cb + 2 * k + 1) * 68 + hw_l]);
        }
        u16* dst = xT + ((size_t)((n << 14) + hw0 + hw_l) << 6) + cb;
        *(uint4*)dst = make_uint4(ou[0], ou[1], ou[2], ou[3]);
        *(uint4*)(dst + 8) = make_uint4(ou[4], ou[5], ou[6], ou[7]);
    } else {
        int i = (blockIdx.x - NB * 256) * 256 + tid;
        if (i < KNN * 2 * 4 * 64 * 8) {
            int j = i & 7, l = (i >> 3) & 63, strip = (i >> 9) & 3,
                chunk = (i >> 11) & 1, kn = i >> 12;
            int oc = strip * 16 + (l & 15);
            int c = chunk * 32 + ((l >> 4) & 3) * 8 + j;
            wf[i] = f2bf(w[(oc * CI + c) * KNN + kn]);
        }
    }
}

// ---- main kernel: block = 8x8 patch (4 waves of 4x4), 64 oc, LDS input tile.
__global__ __launch_bounds__(256, 4) void dcn_main_kernel(const u16* __restrict__ xT,
                                                          const float* __restrict__ off,
                                                          const u16* __restrict__ wf,
                                                          float* __restrict__ out) {
    // 14x16 pixels x 64ch bf16; row stride 68 hw = 136 B (8B-aligned, odd dw-pair)
    __shared__ __align__(16) u16 tile[224 * TSTR];  // 30,464 B
    const int tid = threadIdx.x;
    const int l = tid & 63;
    const int wv = tid >> 6;

    // XCD-affine decode: xcd = blockIdx&7; n = xcd>>1; half = xcd&1.
    const int b = blockIdx.x;
    const int xcd = b & 7;
    const int n = xcd >> 1;
    const int patch = (b >> 3) + ((xcd & 1) << 7);  // 0..255
    const int py = ((patch >> 4) << 3), px = ((patch & 15) << 3);
    const int ty = min(max(py - 3, 0), HH - 14);
    const int tx = min(max(px - 4, 0), WW - 16);

    const u16* xTn = xT + ((size_t)n << 20);
    const float* offn = off + n * (2 * KNN * HW);

    // cooperative tile load: threads 0..223 each move one pixel's 128 B.
    if (tid < 224) {
        const int tr = tid >> 4, tc = tid & 15;
        const u16* src = xTn + ((((ty + tr) << 7) + (tx + tc)) << 6);
        u16* dst = &tile[tid * TSTR];
#pragma unroll
        for (int j = 0; j < 16; j++) {  // 8B-aligned LDS rows -> b64 writes
            *(uint2*)(dst + j * 4) = *(const uint2*)(src + j * 4);
        }
    }

    const int qy = ((wv >> 1) << 2), qx = ((wv & 1) << 2);
    const int col = l & 15;
    const int oh = py + qy + (col >> 2);
    const int ow = px + qx + (col & 3);
    const int rr = (oh << 7) + ow;
    const int cb = (l >> 4) << 3;  // channel base in halfwords: 0,8,16,24

    // preload all 18 offsets (overlaps the tile load)
    float offy[KNN], offx[KNN];
#pragma unroll
    for (int kn = 0; kn < KNN; kn++) {
        offy[kn] = offn[(2 * kn) * HW + rr];
        offx[kn] = offn[(2 * kn + 1) * HW + rr];
    }

    __syncthreads();  // tile resident

    const bf16x8* wfv = (const bf16x8*)wf;
    f32x4 acc[4] = {{0, 0, 0, 0}, {0, 0, 0, 0}, {0, 0, 0, 0}, {0, 0, 0, 0}};

#pragma unroll
    for (int kn = 0; kn < KNN; kn++) {
        float iy = (float)oh + offy[kn], ix = (float)ow + offx[kn];
        float y0f = floorf(iy), x0f = floorf(ix);
        float wy1 = iy - y0f, wy0 = 1.f - wy1;
        float wx1 = ix - x0f, wx0 = 1.f - wx1;
        float my0 = (y0f >= 0.f && y0f <= 127.f) ? 1.f : 0.f;
        float my1 = (y0f >= -1.f && y0f <= 126.f) ? 1.f : 0.f;
        float mx0 = (x0f >= 0.f && x0f <= 127.f) ? 1.f : 0.f;
        float mx1 = (x0f >= -1.f && x0f <= 126.f) ? 1.f : 0.f;
        float W0 = wy0 * wx0 * my0 * mx0, W1 = wy0 * wx1 * my0 * mx1;
        float W2 = wy1 * wx0 * my1 * mx0, W3 = wy1 * wx1 * my1 * mx1;
        int y0 = min(max((int)y0f, 0), 127), y1 = min(max((int)y0f + 1, 0), 127);
        int x0 = min(max((int)x0f, 0), 127), x1 = min(max((int)x0f + 1, 0), 127);

        // tile-local coords (clamped for LDS safety; oot lanes overwritten)
        const int dy0 = min(max(y0 - ty, 0), 13), dy1 = min(max(y1 - ty, 0), 13);
        const int dx0 = min(max(x0 - tx, 0), 15), dx1 = min(max(x1 - tx, 0), 15);
        const int p00 = (dy0 << 4) + dx0, p01 = (dy0 << 4) + dx1;
        const int p10 = (dy1 << 4) + dx0, p11 = (dy1 << 4) + dx1;
        const bool oot = (y0 < ty) | (y1 > ty + 13) | (x0 < tx) | (x1 > tx + 15);

        // 16 ds_read_b64: 4 corners x {chunk0: cb, cb+4; chunk1: cb+32, cb+36}
        uint2 q[16];
#pragma unroll
        for (int cc = 0; cc < 2; cc++) {
            const int o = cb + (cc << 5);
            q[cc * 8 + 0] = *(const uint2*)&tile[p00 * TSTR + o];
            q[cc * 8 + 1] = *(const uint2*)&tile[p00 * TSTR + o + 4];
            q[cc * 8 + 2] = *(const uint2*)&tile[p01 * TSTR + o];
            q[cc * 8 + 3] = *(const uint2*)&tile[p01 * TSTR + o + 4];
            q[cc * 8 + 4] = *(const uint2*)&tile[p10 * TSTR + o];
            q[cc * 8 + 5] = *(const uint2*)&tile[p10 * TSTR + o + 4];
            q[cc * 8 + 6] = *(const uint2*)&tile[p11 * TSTR + o];
            q[cc * 8 + 7] = *(const uint2*)&tile[p11 * TSTR + o + 4];
        }
        if (oot) {  // rare (~0.3% of lanes): exact global gather fallback
            const int O0 = ((y0 << 7) + x0) << 6, O1 = ((y0 << 7) + x1) << 6;
            const int O2 = ((y1 << 7) + x0) << 6, O3 = ((y1 << 7) + x1) << 6;
#pragma unroll
            for (int cc = 0; cc < 2; cc++) {
                const int o = cb + (cc << 5);
                q[cc * 8 + 0] = *(const uint2*)(xTn + O0 + o);
                q[cc * 8 + 1] = *(const uint2*)(xTn + O0 + o + 4);
                q[cc * 8 + 2] = *(const uint2*)(xTn + O1 + o);
                q[cc * 8 + 3] = *(const uint2*)(xTn + O1 + o + 4);
                q[cc * 8 + 4] = *(const uint2*)(xTn + O2 + o);
                q[cc * 8 + 5] = *(const uint2*)(xTn + O2 + o + 4);
                q[cc * 8 + 6] = *(const uint2*)(xTn + O3 + o);
                q[cc * 8 + 7] = *(const uint2*)(xTn + O3 + o + 4);
            }
        }

#pragma unroll
        for (int cc = 0; cc < 2; cc++) {
            union { u32 u[4]; bf16x8 v; } B;
#pragma unroll
            for (int k = 0; k < 4; k++) {  // dword k = q[pair k>>1].{x,y}
                const int hi = k & 1;
                u32 d0 = hi ? q[cc * 8 + 1].y : (k >> 1) ? q[cc * 8 + 1].x
                                                         : (hi ? q[cc * 8 + 0].y : q[cc * 8 + 0].x);
                (void)d0;  // (explicit per-k selection below)
            }
            // dwords of each corner: pair0 = {.x,.y} (dw 0,1), pair1 = (dw 2,3)
            u32 c0d[4] = {q[cc * 8 + 0].x, q[cc * 8 + 0].y, q[cc * 8 + 1].x, q[cc * 8 + 1].y};
            u32 c1d[4] = {q[cc * 8 + 2].x, q[cc * 8 + 2].y, q[cc * 8 + 3].x, q[cc * 8 + 3].y};
            u32 c2d[4] = {q[cc * 8 + 4].x, q[cc * 8 + 4].y, q[cc * 8 + 5].x, q[cc * 8 + 5].y};
            u32 c3d[4] = {q[cc * 8 + 6].x, q[cc * 8 + 6].y, q[cc * 8 + 7].x, q[cc * 8 + 7].y};
#pragma unroll
            for (int k = 0; k < 4; k++) {
                float2 s = up2v(c0d[k]);
                s.x *= W0; s.y *= W0;
                float2 c1 = up2v(c1d[k]);
                s.x = fmaf(c1.x, W1, s.x); s.y = fmaf(c1.y, W1, s.y);
                float2 c2 = up2v(c2d[k]);
                s.x = fmaf(c2.x, W2, s.x); s.y = fmaf(c2.y, W2, s.y);
                float2 c3 = up2v(c3d[k]);
                s.x = fmaf(c3.x, W3, s.x); s.y = fmaf(c3.y, W3, s.y);
                B.u[k] = pkrn(s);
            }
#pragma unroll
            for (int s4 = 0; s4 < 4; s4++) {
                bf16x8 A = wfv[((((kn << 1) + cc) << 2) + s4) * 64 + l];
                acc[s4] = __builtin_amdgcn_mfma_f32_16x16x32_bf16(A, B.v, acc[s4], 0, 0, 0);
            }
        }
    }

    // epilogue: D layout col(pixel)=l&15, row(oc-in-strip)=(l>>4)*4+reg
    const int rq = l >> 4;
    float* op = out + ((size_t)(n * OCH) << 14);
#pragma unroll
    for (int s = 0; s < 4; s++) {
        const int ocb = (s << 4) + (rq << 2);
#pragma unroll
        for (int g = 0; g < 4; g++) {
            op[((ocb + g) << 14) + rr] = acc[s][g];
        }
    }
}

// ---- fallback (ws too small): round-1 style direct kernel
__global__ __launch_bounds__(256) void dcn_fallback_kernel(
    const float* __restrict__ x, const float* __restrict__ off,
    const float* __restrict__ w, float* __restrict__ out) {
    int p = blockIdx.x * blockDim.x + threadIdx.x;
    int n = p / HW, r = p % HW, oh = r / WW, ow = r % WW;
    float acc[OCH];
#pragma unroll
    for (int i = 0; i < OCH; i++) acc[i] = 0.f;
    const float* xn = x + n * (CI * HW);
    const float* offn = off + n * (2 * KNN * HW);
    for (int kn = 0; kn < KNN; kn++) {
        float iy = (float)oh + offn[(2 * kn) * HW + r];
        float ix = (float)ow + offn[(2 * kn + 1) * HW + r];
        float y0f = floorf(iy), x0f = floorf(ix);
        float wy1 = iy - y0f, wy0 = 1.f - wy1, wx1 = ix - x0f, wx0 = 1.f - wx1;
        float my0 = (y0f >= 0.f && y0f <= 127.f) ? 1.f : 0.f;
        float my1 = (y0f >= -1.f && y0f <= 126.f) ? 1.f : 0.f;
        float mx0 = (x0f >= 0.f && x0f <= 127.f) ? 1.f : 0.f;
        float mx1 = (x0f >= -1.f && x0f <= 126.f) ? 1.f : 0.f;
        float w00 = wy0 * wx0 * my0 * mx0, w01 = wy0 * wx1 * my0 * mx1;
        float w10 = wy1 * wx0 * my1 * mx0, w11 = wy1 * wx1 * my1 * mx1;
        int y0 = min(max((int)y0f, 0), 127), y1 = min(max((int)y0f + 1, 0), 127);
        int x0 = min(max((int)x0f, 0), 127), x1 = min(max((int)x0f + 1, 0), 127);
        int o00 = y0 * WW + x0, o01 = y0 * WW + x1, o10 = y1 * WW + x0, o11 = y1 * WW + x1;
        for (int c = 0; c < CI; c++) {
            const float* xc = xn + c * HW;
            float s = xc[o00] * w00 + xc[o01] * w01 + xc[o10] * w10 + xc[o11] * w11;
#pragma unroll
            for (int oc = 0; oc < OCH; oc++) acc[oc] += w[(oc * CI + c) * KNN + kn] * s;
        }
    }
    float* outp = out + n * (OCH * HW) + r;
#pragma unroll
    for (int oc = 0; oc < OCH; oc++) outp[oc * HW] = acc[oc];
}

extern "C" void kernel_launch(void* const* d_in, const int* in_sizes, int n_in,
                              void* d_out, int out_size, void* d_ws, size_t ws_size,
                              hipStream_t stream) {
    const float* x = (const float*)d_in[0];
    const float* off = (const float*)d_in[1];
    const float* w = (const float*)d_in[2];
    float* out = (float*)d_out;

    const size_t xT_elems = (size_t)NB * HW * CI;             // 4,194,304 u16
    const size_t wf_elems = (size_t)KNN * 2 * 4 * 64 * 8;     // 36,864 u16
    const size_t need = (xT_elems + wf_elems) * sizeof(u16);  // ~8.46 MB

    if (ws_size >= need) {
        u16* xT = (u16*)d_ws;
        u16* wfr = xT + xT_elems;
        const int wf_blocks = (int)((wf_elems + 255) / 256);  // 144
        prep_kernel<<<NB * 256 + wf_blocks, 256, 0, stream>>>(x, w, xT, wfr);
        dcn_main_kernel<<<NB * 256, 256, 0, stream>>>(xT, off, wfr, out);
    } else {
        dcn_fallback_kernel<<<(NB * HW) / 256, 256, 0, stream>>>(x, off, w, out);
    }
}

// Round 10
// 99.815 us; speedup vs baseline: 1.7613x; 1.0165x over previous
//
#include <hip/hip_runtime.h>
#include <hip/hip_bf16.h>

// Deformable conv2d (v1, align_corners=True, zeros padding), NHWC-bf16 + MFMA.
// R10 = R9 with the LDS tile re-laid-out to kill structural bank conflicts:
//  - pixel row = exactly 32 dwords (128 B, no pad); 16B chunk q stored at
//    (q ^ (p&7)) -> distinct p&7 hits distinct bank groups (R8/R9 strides
//    36/34 dw confined reads to 8/16 of 32 banks: 3-5x serialization on every
//    corner read -> ~20us of main's ~35us).
//  - corner reads: 8 ds_read_b128 per kn (was 16 ds_read_b64).
//  - tile load: uint4 global reads + swizzled b128 LDS writes.
// x(4,64,128,128) f32, offset(4,18,128,128) f32, weight(64,64,9) f32
// -> out(4,64,128,128) f32.  iy = oh + off_y, ix = ow + off_x.

#define NB 4
#define CI 64
#define HH 128
#define WW 128
#define OCH 64
#define KNN 9
#define HW (HH * WW)

typedef unsigned int u32;
typedef unsigned short u16;
typedef __attribute__((ext_vector_type(8))) short bf16x8;
typedef __attribute__((ext_vector_type(4))) float f32x4;

__device__ inline u16 f2bf(float f) {  // RNE
    u32 u = __float_as_uint(f);
    return (u16)((u + 0x7fffu + ((u >> 16) & 1u)) >> 16);
}
__device__ inline u32 pk2(float lo, float hi) {
    return (u32)f2bf(lo) | ((u32)f2bf(hi) << 16);
}
__device__ inline float2 up2v(u32 u) {
    return float2{__uint_as_float(u << 16), __uint_as_float(u & 0xffff0000u)};
}
__device__ inline u32 pkrn(float2 s) {
    union { __hip_bfloat162 b; u32 u; } c;
    c.b = __float22bfloat162_rn(s);
    return c.u;
}

// ---- prologue: x NCHW f32 -> NHWC bf16, + weight -> A-fragment order bf16.
// wf layout: frag[kn][chunk(2)][strip(4)][lane(64)][j(8)]; lane holds
// A[m=lane&15][k=(lane>>4)*8+j], oc = strip*16+m, c = chunk*32+k.
__global__ __launch_bounds__(256) void prep_kernel(const float* __restrict__ x,
                                                   const float* __restrict__ w,
                                                   u16* __restrict__ xT,
                                                   u16* __restrict__ wf) {
    __shared__ float T[64 * 68];
    const int tid = threadIdx.x;
    if (blockIdx.x < NB * 256) {
        const int n = blockIdx.x >> 8;
        const int hw0 = (blockIdx.x & 255) << 6;
#pragma unroll
        for (int jj = 0; jj < 4; jj++) {
            int c = (tid >> 4) + (jj << 4);
            int hwq = (tid & 15) << 2;
            float4 v = *(const float4*)&x[(((n << 6) + c) << 14) + hw0 + hwq];
            *(float4*)&T[c * 68 + hwq] = v;
        }
        __syncthreads();
        const int hw_l = tid >> 2;
        const int cb = (tid & 3) << 4;
        u32 ou[8];
#pragma unroll
        for (int k = 0; k < 8; k++) {
            ou[k] = pk2(T[(cb + 2 * k) * 68 + hw_l], T[(cb + 2 * k + 1) * 68 + hw_l]);
        }
        u16* dst = xT + ((size_t)((n << 14) + hw0 + hw_l) << 6) + cb;
        *(uint4*)dst = make_uint4(ou[0], ou[1], ou[2], ou[3]);
        *(uint4*)(dst + 8) = make_uint4(ou[4], ou[5], ou[6], ou[7]);
    } else {
        int i = (blockIdx.x - NB * 256) * 256 + tid;
        if (i < KNN * 2 * 4 * 64 * 8) {
            int j = i & 7, l = (i >> 3) & 63, strip = (i >> 9) & 3,
                chunk = (i >> 11) & 1, kn = i >> 12;
            int oc = strip * 16 + (l & 15);
            int c = chunk * 32 + ((l >> 4) & 3) * 8 + j;
            wf[i] = f2bf(w[(oc * CI + c) * KNN + kn]);
        }
    }
}

// ---- main kernel: block = 8x8 patch (4 waves of 4x4), 64 oc, LDS input tile.
__global__ __launch_bounds__(256, 4) void dcn_main_kernel(const u16* __restrict__ xT,
                                                          const float* __restrict__ off,
                                                          const u16* __restrict__ wf,
                                                          float* __restrict__ out) {
    // 14x16 pixels x 64ch bf16; pixel row = 32 dw (128B); chunk q at q^(p&7).
    __shared__ __align__(16) u32 tile[224 * 32];  // 28,672 B
    const int tid = threadIdx.x;
    const int l = tid & 63;
    const int wv = tid >> 6;

    // XCD-affine decode: xcd = blockIdx&7; n = xcd>>1; half = xcd&1.
    const int b = blockIdx.x;
    const int xcd = b & 7;
    const int n = xcd >> 1;
    const int patch = (b >> 3) + ((xcd & 1) << 7);  // 0..255
    const int py = ((patch >> 4) << 3), px = ((patch & 15) << 3);
    const int ty = min(max(py - 3, 0), HH - 14);
    const int tx = min(max(px - 4, 0), WW - 16);

    const u16* xTn = xT + ((size_t)n << 20);
    const float* offn = off + n * (2 * KNN * HW);

    // cooperative tile load: threads 0..223 each move one pixel's 128 B,
    // chunk j (16B) lands at slot j^(p&7).
    if (tid < 224) {
        const int tr = tid >> 4, tc = tid & 15;
        const u16* src = xTn + ((((ty + tr) << 7) + (tx + tc)) << 6);
        u32* dst = &tile[tid << 5];
        const int sw = tid & 7;
#pragma unroll
        for (int j = 0; j < 8; j++) {
            *(uint4*)&dst[(j ^ sw) << 2] = *(const uint4*)(src + (j << 3));
        }
    }

    const int qy = ((wv >> 1) << 2), qx = ((wv & 1) << 2);
    const int col = l & 15;
    const int oh = py + qy + (col >> 2);
    const int ow = px + qx + (col & 3);
    const int rr = (oh << 7) + ow;
    const int qc = l >> 4;          // channel chunk index 0..3 (16B chunks)
    const int cb = qc << 3;         // channel base in halfwords

    // preload all 18 offsets (overlaps the tile load)
    float offy[KNN], offx[KNN];
#pragma unroll
    for (int kn = 0; kn < KNN; kn++) {
        offy[kn] = offn[(2 * kn) * HW + rr];
        offx[kn] = offn[(2 * kn + 1) * HW + rr];
    }

    __syncthreads();  // tile resident

    const bf16x8* wfv = (const bf16x8*)wf;
    f32x4 acc[4] = {{0, 0, 0, 0}, {0, 0, 0, 0}, {0, 0, 0, 0}, {0, 0, 0, 0}};

#pragma unroll
    for (int kn = 0; kn < KNN; kn++) {
        float iy = (float)oh + offy[kn], ix = (float)ow + offx[kn];
        float y0f = floorf(iy), x0f = floorf(ix);
        float wy1 = iy - y0f, wy0 = 1.f - wy1;
        float wx1 = ix - x0f, wx0 = 1.f - wx1;
        float my0 = (y0f >= 0.f && y0f <= 127.f) ? 1.f : 0.f;
        float my1 = (y0f >= -1.f && y0f <= 126.f) ? 1.f : 0.f;
        float mx0 = (x0f >= 0.f && x0f <= 127.f) ? 1.f : 0.f;
        float mx1 = (x0f >= -1.f && x0f <= 126.f) ? 1.f : 0.f;
        float W0 = wy0 * wx0 * my0 * mx0, W1 = wy0 * wx1 * my0 * mx1;
        float W2 = wy1 * wx0 * my1 * mx0, W3 = wy1 * wx1 * my1 * mx1;
        int y0 = min(max((int)y0f, 0), 127), y1 = min(max((int)y0f + 1, 0), 127);
        int x0 = min(max((int)x0f, 0), 127), x1 = min(max((int)x0f + 1, 0), 127);

        // tile-local coords (clamped for LDS safety; oot lanes overwritten)
        const int dy0 = min(max(y0 - ty, 0), 13), dy1 = min(max(y1 - ty, 0), 13);
        const int dx0 = min(max(x0 - tx, 0), 15), dx1 = min(max(x1 - tx, 0), 15);
        const int P0 = (dy0 << 4) + dx0, P1 = (dy0 << 4) + dx1;
        const int P2 = (dy1 << 4) + dx0, P3 = (dy1 << 4) + dx1;
        const bool oot = (y0 < ty) | (y1 > ty + 13) | (x0 < tx) | (x1 > tx + 15);

        // 8 ds_read_b128: 4 corners x 2 channel-chunks (q = qc, qc+4), swizzled
        uint4 Q0a = *(const uint4*)&tile[(P0 << 5) + (((qc    ) ^ (P0 & 7)) << 2)];
        uint4 Q0b = *(const uint4*)&tile[(P0 << 5) + (((qc + 4) ^ (P0 & 7)) << 2)];
        uint4 Q1a = *(const uint4*)&tile[(P1 << 5) + (((qc    ) ^ (P1 & 7)) << 2)];
        uint4 Q1b = *(const uint4*)&tile[(P1 << 5) + (((qc + 4) ^ (P1 & 7)) << 2)];
        uint4 Q2a = *(const uint4*)&tile[(P2 << 5) + (((qc    ) ^ (P2 & 7)) << 2)];
        uint4 Q2b = *(const uint4*)&tile[(P2 << 5) + (((qc + 4) ^ (P2 & 7)) << 2)];
        uint4 Q3a = *(const uint4*)&tile[(P3 << 5) + (((qc    ) ^ (P3 & 7)) << 2)];
        uint4 Q3b = *(const uint4*)&tile[(P3 << 5) + (((qc + 4) ^ (P3 & 7)) << 2)];
        if (oot) {  // rare (~0.3% of lane-kn): exact global gather fallback
            const int O0 = ((y0 << 7) + x0) << 6, O1 = ((y0 << 7) + x1) << 6;
            const int O2 = ((y1 << 7) + x0) << 6, O3 = ((y1 << 7) + x1) << 6;
            Q0a = *(const uint4*)(xTn + O0 + cb);
            Q0b = *(const uint4*)(xTn + O0 + cb + 32);
            Q1a = *(const uint4*)(xTn + O1 + cb);
            Q1b = *(const uint4*)(xTn + O1 + cb + 32);
            Q2a = *(const uint4*)(xTn + O2 + cb);
            Q2b = *(const uint4*)(xTn + O2 + cb + 32);
            Q3a = *(const uint4*)(xTn + O3 + cb);
            Q3b = *(const uint4*)(xTn + O3 + cb + 32);
        }

#pragma unroll
        for (int cc = 0; cc < 2; cc++) {
            const u32* c0 = (const u32*)(cc ? &Q0b : &Q0a);
            const u32* c1 = (const u32*)(cc ? &Q1b : &Q1a);
            const u32* c2 = (const u32*)(cc ? &Q2b : &Q2a);
            const u32* c3 = (const u32*)(cc ? &Q3b : &Q3a);
            union { u32 u[4]; bf16x8 v; } B;
#pragma unroll
            for (int k = 0; k < 4; k++) {
                float2 s = up2v(c0[k]);
                s.x *= W0; s.y *= W0;
                float2 t1 = up2v(c1[k]);
                s.x = fmaf(t1.x, W1, s.x); s.y = fmaf(t1.y, W1, s.y);
                float2 t2 = up2v(c2[k]);
                s.x = fmaf(t2.x, W2, s.x); s.y = fmaf(t2.y, W2, s.y);
                float2 t3 = up2v(c3[k]);
                s.x = fmaf(t3.x, W3, s.x); s.y = fmaf(t3.y, W3, s.y);
                B.u[k] = pkrn(s);
            }
#pragma unroll
            for (int s4 = 0; s4 < 4; s4++) {
                bf16x8 A = wfv[((((kn << 1) + cc) << 2) + s4) * 64 + l];
                acc[s4] = __builtin_amdgcn_mfma_f32_16x16x32_bf16(A, B.v, acc[s4], 0, 0, 0);
            }
        }
    }

    // epilogue: D layout col(pixel)=l&15, row(oc-in-strip)=(l>>4)*4+reg
    const int rq = l >> 4;
    float* op = out + ((size_t)(n * OCH) << 14);
#pragma unroll
    for (int s = 0; s < 4; s++) {
        const int ocb = (s << 4) + (rq << 2);
#pragma unroll
        for (int g = 0; g < 4; g++) {
            op[((ocb + g) << 14) + rr] = acc[s][g];
        }
    }
}

// ---- fallback (ws too small): round-1 style direct kernel
__global__ __launch_bounds__(256) void dcn_fallback_kernel(
    const float* __restrict__ x, const float* __restrict__ off,
    const float* __restrict__ w, float* __restrict__ out) {
    int p = blockIdx.x * blockDim.x + threadIdx.x;
    int n = p / HW, r = p % HW, oh = r / WW, ow = r % WW;
    float acc[OCH];
#pragma unroll
    for (int i = 0; i < OCH; i++) acc[i] = 0.f;
    const float* xn = x + n * (CI * HW);
    const float* offn = off + n * (2 * KNN * HW);
    for (int kn = 0; kn < KNN; kn++) {
        float iy = (float)oh + offn[(2 * kn) * HW + r];
        float ix = (float)ow + offn[(2 * kn + 1) * HW + r];
        float y0f = floorf(iy), x0f = floorf(ix);
        float wy1 = iy - y0f, wy0 = 1.f - wy1, wx1 = ix - x0f, wx0 = 1.f - wx1;
        float my0 = (y0f >= 0.f && y0f <= 127.f) ? 1.f : 0.f;
        float my1 = (y0f >= -1.f && y0f <= 126.f) ? 1.f : 0.f;
        float mx0 = (x0f >= 0.f && x0f <= 127.f) ? 1.f : 0.f;
        float mx1 = (x0f >= -1.f && x0f <= 126.f) ? 1.f : 0.f;
        float w00 = wy0 * wx0 * my0 * mx0, w01 = wy0 * wx1 * my0 * mx1;
        float w10 = wy1 * wx0 * my1 * mx0, w11 = wy1 * wx1 * my1 * mx1;
        int y0 = min(max((int)y0f, 0), 127), y1 = min(max((int)y0f + 1, 0), 127);
        int x0 = min(max((int)x0f, 0), 127), x1 = min(max((int)x0f + 1, 0), 127);
        int o00 = y0 * WW + x0, o01 = y0 * WW + x1, o10 = y1 * WW + x0, o11 = y1 * WW + x1;
        for (int c = 0; c < CI; c++) {
            const float* xc = xn + c * HW;
            float s = xc[o00] * w00 + xc[o01] * w01 + xc[o10] * w10 + xc[o11] * w11;
#pragma unroll
            for (int oc = 0; oc < OCH; oc++) acc[oc] += w[(oc * CI + c) * KNN + kn] * s;
        }
    }
    float* outp = out + n * (OCH * HW) + r;
#pragma unroll
    for (int oc = 0; oc < OCH; oc++) outp[oc * HW] = acc[oc];
}

extern "C" void kernel_launch(void* const* d_in, const int* in_sizes, int n_in,
                              void* d_out, int out_size, void* d_ws, size_t ws_size,
                              hipStream_t stream) {
    const float* x = (const float*)d_in[0];
    const float* off = (const float*)d_in[1];
    const float* w = (const float*)d_in[2];
    float* out = (float*)d_out;

    const size_t xT_elems = (size_t)NB * HW * CI;             // 4,194,304 u16
    const size_t wf_elems = (size_t)KNN * 2 * 4 * 64 * 8;     // 36,864 u16
    const size_t need = (xT_elems + wf_elems) * sizeof(u16);  // ~8.46 MB

    if (ws_size >= need) {
        u16* xT = (u16*)d_ws;
        u16* wfr = xT + xT_elems;
        const int wf_blocks = (int)((wf_elems + 255) / 256);  // 144
        prep_kernel<<<NB * 256 + wf_blocks, 256, 0, stream>>>(x, w, xT, wfr);
        dcn_main_kernel<<<NB * 256, 256, 0, stream>>>(xT, off, wfr, out);
    } else {
        dcn_fallback_kernel<<<(NB * HW) / 256, 256, 0, stream>>>(x, off, w, out);
    }
}